// Round 2
// baseline (1462.423 us; speedup 1.0000x reference)
//
#include <hip/hip_runtime.h>
#include <hip/hip_cooperative_groups.h>

namespace cg = cooperative_groups;

// SST input layer, fully fused into one cooperative kernel.
// Config: WIN=12, GRID=468, BATCH=4, shifts (0,0),(6,6), MAX_WIN_Y=40,
// window ids in [0, 6400). DROP: c<30->lvl0,t30; c<60->lvl1,t60;
// c<100000->lvl2,t100; else lvl-1,t0.

#define NWIN 6400
#define CAP 2048          // per-window LDS member cap (8 KB); real max count ~100
#define GRID_BLOCKS 1024  // 4 blocks/CU co-resident (launch_bounds caps VGPR<=128)

__device__ __forceinline__ int drop_target(int lvl) {
    return (lvl == 0) ? 30 : (lvl == 1) ? 60 : (lvl == 2) ? 100 : 0;
}

__device__ void scan_block(const int* __restrict__ cnt, int* __restrict__ base,
                           int* __restrict__ lvlW, int* psum) {
    int t = threadIdx.x;
    int st = t * 25;                     // 256*25 = 6400
    int s = 0;
    for (int j = 0; j < 25; j++) s += cnt[st + j];
    psum[t] = s;
    __syncthreads();
    if (t == 0) {
        int acc = 0;
        for (int j = 0; j < 256; j++) { int v = psum[j]; psum[j] = acc; acc += v; }
    }
    __syncthreads();
    int acc = psum[t];
    for (int j = 0; j < 25; j++) {
        int w = st + j;
        int c = cnt[w];
        base[w] = acc;
        acc += c;
        lvlW[w] = (c < 30) ? 0 : (c < 60) ? 1 : (c < 100000) ? 2 : -1;
    }
    __syncthreads();
}

__device__ void conti_block(const int* __restrict__ lvlW, const int* __restrict__ keptC,
                            int* __restrict__ conti, int* pc0, int* pc1, int* pc2) {
    int t = threadIdx.x;
    int st = t * 25;
    int c0 = 0, c1 = 0, c2 = 0;
    for (int j = 0; j < 25; j++) {
        int w = st + j;
        if (keptC[w] > 0) {
            int l = lvlW[w];
            c0 += (l == 0); c1 += (l == 1); c2 += (l == 2);
        }
    }
    pc0[t] = c0; pc1[t] = c1; pc2[t] = c2;
    __syncthreads();
    if (t == 0) {
        int a = 0, b = 0, c = 0;
        for (int j = 0; j < 256; j++) {
            int v0 = pc0[j], v1 = pc1[j], v2 = pc2[j];
            pc0[j] = a; pc1[j] = b; pc2[j] = c;
            a += v0; b += v1; c += v2;
        }
    }
    __syncthreads();
    int a0 = pc0[t], a1 = pc1[t], a2 = pc2[t];
    for (int j = 0; j < 25; j++) {
        int w = st + j;
        int l = lvlW[w];
        conti[w] = (l == 0) ? a0 : (l == 1) ? a1 : (l == 2) ? a2 : 0;
        if (keptC[w] > 0) {
            if (l == 0) a0++; else if (l == 1) a1++; else if (l == 2) a2++;
        }
    }
    __syncthreads();
}

__global__ __launch_bounds__(256, 4) void sst_fused(
    const float4* __restrict__ feat, const int* __restrict__ coors, int n,
    float* __restrict__ out, int* __restrict__ ws,
    int lo, int hi, int coop)
{
    cg::grid_group grid = cg::this_grid();
    const int tid = threadIdx.x;
    const int gsz = gridDim.x * blockDim.x;
    const int gid = blockIdx.x * blockDim.x + tid;

    int* cnt0   = ws;
    int* cur0   = ws + NWIN;
    int* cnt1   = ws + 2 * NWIN;
    int* cur1   = ws + 3 * NWIN;
    int* keptC0 = ws + 4 * NWIN;
    int* keptC1 = ws + 5 * NWIN;
    int* base0  = ws + 6 * NWIN;
    int* base1  = ws + 7 * NWIN;
    int* lvlW0  = ws + 8 * NWIN;
    int* lvlW1  = ws + 9 * NWIN;
    int* conti0 = ws + 10 * NWIN;
    int* conti1 = ws + 11 * NWIN;
    int* arr    = ws + 12 * NWIN;
    int* w0a   = arr;
    int* w1a   = arr + n;
    int* seg0  = arr + 2 * n;
    int* seg1  = arr + 3 * n;
    int* keep0 = arr + 4 * n;
    int* keep1 = arr + 5 * n;
    int* rk0   = arr + 6 * n;
    int* rk1   = arr + 7 * n;

    __shared__ int lds[CAP];
    __shared__ int pc0[256], pc1[256], pc2[256];

#define PHASE_IN(p) ((p) >= lo && (p) < hi)

    // ---- P0: zero counters (cnt0,cur0,cnt1,cur1,keptC0,keptC1) ----
    if (PHASE_IN(0)) {
        for (int i = gid; i < 6 * NWIN; i += gsz) cnt0[i] = 0;
        if (coop) grid.sync();
    }

    // ---- P1: window ids for both shifts + shift-0 histogram ----
    if (PHASE_IN(1)) {
        const int4* c4 = (const int4*)coors;
        for (int i = gid; i < n; i += gsz) {
            int4 c = c4[i];                  // b, z, y, x
            int w0 = c.x * 1600 + (c.w / 12) * 40 + (c.z / 12);
            int w1 = c.x * 1600 + ((c.w + 6) / 12) * 40 + ((c.z + 6) / 12);
            w0a[i] = w0;
            w1a[i] = w1;
            atomicAdd(&cnt0[w0], 1);
        }
        if (coop) grid.sync();
    }

    // ---- P2: exclusive scan of cnt0 + shift-0 window level ----
    if (PHASE_IN(2)) {
        if (blockIdx.x == 0) scan_block(cnt0, base0, lvlW0, pc0);
        if (coop) grid.sync();
    }

    // ---- P3: scatter voxel ids into shift-0 window segments ----
    if (PHASE_IN(3)) {
        for (int i = gid; i < n; i += gsz) {
            int w = w0a[i];
            int p = atomicAdd(&cur0[w], 1);
            seg0[base0[w] + p] = i;
        }
        if (coop) grid.sync();
    }

    // ---- P4: per-window shift-0 rank -> keep0; survivors feed cnt1 ----
    if (PHASE_IN(4)) {
        for (int w = blockIdx.x; w < NWIN; w += gridDim.x) {
            int k = cnt0[w];
            if (k == 0) continue;
            int bs = base0[w];
            int target = drop_target(lvlW0[w]);
            if (k <= CAP) {
                for (int j = tid; j < k; j += 256) lds[j] = seg0[bs + j];
                __syncthreads();
                for (int e = tid; e < k; e += 256) {
                    int v = lds[e];
                    int r = 0;
                    for (int j = 0; j < k; j++) r += (lds[j] < v);
                    int kp = (r < target) ? 1 : 0;
                    keep0[v] = kp;
                    if (kp) atomicAdd(&cnt1[w1a[v]], 1);
                }
                __syncthreads();
            } else {
                for (int e = tid; e < k; e += 256) {
                    int v = seg0[bs + e];
                    int r = 0;
                    for (int j = 0; j < k; j++) r += (seg0[bs + j] < v);
                    int kp = (r < target) ? 1 : 0;
                    keep0[v] = kp;
                    if (kp) atomicAdd(&cnt1[w1a[v]], 1);
                }
            }
        }
        if (coop) grid.sync();
    }

    // ---- P5: exclusive scan of cnt1 + shift-1 window level ----
    if (PHASE_IN(5)) {
        if (blockIdx.x == 0) scan_block(cnt1, base1, lvlW1, pc0);
        if (coop) grid.sync();
    }

    // ---- P6: scatter shift-0 survivors into shift-1 segments ----
    if (PHASE_IN(6)) {
        for (int i = gid; i < n; i += gsz) {
            if (!keep0[i]) continue;
            int w = w1a[i];
            int p = atomicAdd(&cur1[w], 1);
            seg1[base1[w] + p] = i;
        }
        if (coop) grid.sync();
    }

    // ---- P7: shift-1 windows: keep1, rk1, keptC1; kept feed keptC0 ----
    if (PHASE_IN(7)) {
        for (int w = blockIdx.x; w < NWIN; w += gridDim.x) {
            int k = cnt1[w];
            if (k == 0) continue;
            int bs = base1[w];
            int target = drop_target(lvlW1[w]);
            if (k <= CAP) {
                for (int j = tid; j < k; j += 256) lds[j] = seg1[bs + j];
                __syncthreads();
                int kparr[(CAP + 255) / 256];
                int q = 0;
                for (int e = tid; e < k; e += 256, q++) {
                    int v = lds[e];
                    int r = 0;
                    for (int j = 0; j < k; j++) r += (lds[j] < v);
                    int kp = (r < target) ? 1 : 0;
                    keep1[v] = kp;
                    kparr[q] = kp;
                }
                __syncthreads();
                q = 0;
                for (int e = tid; e < k; e += 256, q++) lds[e] |= (kparr[q] << 30);
                __syncthreads();
                for (int e = tid; e < k; e += 256) {
                    int enc = lds[e];
                    if (enc >> 30) {
                        int v = enc & 0x3FFFFFFF;
                        int r = 0;
                        for (int j = 0; j < k; j++) {
                            int ej = lds[j];
                            r += (ej >> 30) & (int)((ej & 0x3FFFFFFF) < v);
                        }
                        rk1[v] = r;
                        atomicAdd(&keptC0[w0a[v]], 1);
                    }
                }
                if (tid == 0) {
                    int s = 0;
                    for (int j = 0; j < k; j++) s += lds[j] >> 30;
                    keptC1[w] = s;
                }
                __syncthreads();
            } else {
                for (int e = tid; e < k; e += 256) {
                    int v = seg1[bs + e];
                    int r = 0;
                    for (int j = 0; j < k; j++) r += (seg1[bs + j] < v);
                    keep1[v] = (r < target) ? 1 : 0;
                }
                __syncthreads();
                for (int e = tid; e < k; e += 256) {
                    int v = seg1[bs + e];
                    if (!keep1[v]) continue;
                    int r = 0;
                    for (int j = 0; j < k; j++) {
                        int u = seg1[bs + j];
                        r += (keep1[u] && (u < v)) ? 1 : 0;
                    }
                    rk1[v] = r;
                    atomicAdd(&keptC0[w0a[v]], 1);
                }
                if (tid == 0) {
                    int s = 0;
                    for (int j = 0; j < k; j++) s += keep1[seg1[bs + j]] ? 1 : 0;
                    keptC1[w] = s;
                }
                __syncthreads();
            }
        }
        if (coop) grid.sync();
    }

    // ---- P8: conti (blocks 0,1) || rk0 windows (blocks >=2) || feat copy ----
    if (PHASE_IN(8)) {
        if (blockIdx.x == 0) {
            conti_block(lvlW0, keptC0, conti0, pc0, pc1, pc2);
        } else if (blockIdx.x == 1) {
            conti_block(lvlW1, keptC1, conti1, pc0, pc1, pc2);
        } else {
            for (int w = (int)blockIdx.x - 2; w < NWIN; w += (int)gridDim.x - 2) {
                int k = cnt0[w];
                if (k == 0) continue;
                int bs = base0[w];
                if (k <= CAP) {
                    for (int j = tid; j < k; j += 256) {
                        int v = seg0[bs + j];
                        int k0 = keep0[v];
                        int kf = k0 ? (keep1[v] != 0) : 0;
                        lds[j] = v | (kf << 30);
                    }
                    __syncthreads();
                    for (int e = tid; e < k; e += 256) {
                        int enc = lds[e];
                        if (enc >> 30) {
                            int v = enc & 0x3FFFFFFF;
                            int r = 0;
                            for (int j = 0; j < k; j++) {
                                int ej = lds[j];
                                r += (ej >> 30) & (int)((ej & 0x3FFFFFFF) < v);
                            }
                            rk0[v] = r;
                        }
                    }
                    __syncthreads();
                } else {
                    for (int e = tid; e < k; e += 256) {
                        int v = seg0[bs + e];
                        if (!keep0[v] || !keep1[v]) continue;
                        int r = 0;
                        for (int j = 0; j < k; j++) {
                            int u = seg0[bs + j];
                            int kq = keep0[u] ? (keep1[u] != 0) : 0;
                            r += kq & (int)(u < v);
                        }
                        rk0[v] = r;
                    }
                }
            }
        }
        // everyone: vectorized masked feat copy (the HBM-bound bulk)
        float4* out4 = (float4*)out;
        int total = n * 32;                    // 128 floats = 32 float4 per row
        for (int i = gid; i < total; i += gsz) {
            int row = i >> 5;
            float4 v = feat[i];
            int k0 = keep0[row];
            int kf = k0 ? keep1[row] : 0;
            if (!kf) { v.x = 0.f; v.y = 0.f; v.z = 0.f; v.w = 0.f; }
            out4[i] = v;
        }
        if (coop) grid.sync();
    }

    // ---- P9: per-voxel scalar outputs ----
    if (PHASE_IN(9)) {
        float* o = out + (size_t)n * 128;
        for (int i = gid; i < n; i += gsz) {
            int w0 = w0a[i], w1 = w1a[i];
            int k0 = keep0[i];
            int kf = k0 ? (keep1[i] ? 1 : 0) : 0;
            int l0 = lvlW0[w0];
            int l1 = k0 ? lvlW1[w1] : -1;
            int f0 = -1, f1 = -1;
            if (kf) {
                int mt0 = (l0 == 0) ? 30 : (l0 == 1) ? 60 : 100;
                int mt1 = (l1 == 0) ? 30 : (l1 == 1) ? 60 : 100;
                f0 = conti0[w0] * mt0 + rk0[i];
                f1 = conti1[w1] * mt1 + rk1[i];
            }
            o[i]         = (float)kf;
            o[n + i]     = (float)l0;
            o[2 * n + i] = (float)l1;
            o[3 * n + i] = (float)w0;
            o[4 * n + i] = (float)w1;
            o[5 * n + i] = (float)f0;
            o[6 * n + i] = (float)f1;
        }
    }
#undef PHASE_IN
}

extern "C" void kernel_launch(void* const* d_in, const int* in_sizes, int n_in,
                              void* d_out, int out_size, void* d_ws, size_t ws_size,
                              hipStream_t stream) {
    (void)n_in; (void)out_size; (void)ws_size;
    const float4* feat = (const float4*)d_in[0];
    const int* coors   = (const int*)d_in[1];
    int n = in_sizes[1] / 4;
    float* out = (float*)d_out;
    int* ws = (int*)d_ws;

    int lo = 0, hi = 10, coop = 1;
    void* args[] = { (void*)&feat, (void*)&coors, (void*)&n, (void*)&out,
                     (void*)&ws, (void*)&lo, (void*)&hi, (void*)&coop };
    hipError_t err = hipLaunchCooperativeKernel(
        reinterpret_cast<void*>(sst_fused), dim3(GRID_BLOCKS), dim3(256),
        args, 0, stream);
    if (err != hipSuccess) {
        // fallback: one normal launch per phase (kernel boundaries = barriers)
        for (int p = 0; p < 10; p++) {
            sst_fused<<<GRID_BLOCKS, 256, 0, stream>>>(feat, coors, n, out, ws,
                                                       p, p + 1, 0);
        }
    }
}